// Round 2
// baseline (298.244 us; speedup 1.0000x reference)
//
#include <hip/hip_runtime.h>

typedef __attribute__((ext_vector_type(8))) short short8;
typedef __attribute__((ext_vector_type(4))) float f32x4;
typedef __attribute__((ext_vector_type(16))) float f32x16;
typedef unsigned short u16;
typedef unsigned int u32;

__device__ __forceinline__ float bf2f(u16 u) {
    union { u32 i; float f; } x;
    x.i = ((u32)u) << 16;
    return x.f;
}

__device__ __forceinline__ u16 f2bf(float f) {
    union { float f; u32 i; } x;
    x.f = f;
    u32 r = x.i + 0x7fffu + ((x.i >> 16) & 1u);  // RNE
    return (u16)(r >> 16);
}

// packed f32x2 -> bf16x2 (RNE), one instruction
__device__ __forceinline__ u32 cvt_pk_bf16(float lo, float hi) {
    u32 d;
    asm("v_cvt_pk_bf16_f32 %0, %1, %2" : "=v"(d) : "v"(lo), "v"(hi));
    return d;
}

// after pswap(a,b):  a' = lane<32 ? a(own) : b(lane-32)
//                    b' = lane<32 ? a(lane+32) : b(own)
__device__ __forceinline__ void pswap(u32& a, u32& b) {
#if __has_builtin(__builtin_amdgcn_permlane32_swap)
    auto r = __builtin_amdgcn_permlane32_swap(a, b, false, false);
    a = r[0];
    b = r[1];
#else
    const int l = (int)(threadIdx.x & 63);
    const u32 ax = __shfl(a, l ^ 32);
    const u32 bx = __shfl(b, l ^ 32);
    a = (l < 32) ? a : bx;
    b = (l < 32) ? ax : b;
#endif
}

#if __has_builtin(__builtin_amdgcn_exp2f)
#define EXP2F(x) __builtin_amdgcn_exp2f(x)
#else
#define EXP2F(x) exp2f(x)
#endif

// ---------------------------------------------------------------------------
// fp32 -> bf16 elementwise (n divisible by 2048)
// ---------------------------------------------------------------------------
__global__ __launch_bounds__(256) void convert_bf16(const float* __restrict__ in,
                                                    u16* __restrict__ out) {
    const long i = ((long)blockIdx.x * 256 + threadIdx.x) * 8;
    f32x4 v0 = *(const f32x4*)(in + i);
    f32x4 v1 = *(const f32x4*)(in + i + 4);
    short8 o;
#pragma unroll
    for (int j = 0; j < 4; ++j) o[j] = (short)f2bf(v0[j]);
#pragma unroll
    for (int j = 0; j < 4; ++j) o[4 + j] = (short)f2bf(v1[j]);
    *(short8*)(out + i) = o;
}

// ---------------------------------------------------------------------------
// fp32 [K][N] -> bf16 [N][K] transpose+convert
// ---------------------------------------------------------------------------
__global__ __launch_bounds__(256) void transpose_f32_bf16(const float* __restrict__ in,
                                                          u16* __restrict__ out,
                                                          int K, int N) {
    __shared__ float tile[32][33];
    const int nb = blockIdx.x * 32, kb = blockIdx.y * 32;
    const int tx = threadIdx.x, ty = threadIdx.y;  // 32 x 8
#pragma unroll
    for (int i = 0; i < 32; i += 8)
        tile[ty + i][tx] = in[(long)(kb + ty + i) * N + nb + tx];
    __syncthreads();
#pragma unroll
    for (int i = 0; i < 32; i += 8)
        out[(long)(nb + ty + i) * K + kb + tx] = f2bf(tile[tx][ty + i]);
}

// ---------------------------------------------------------------------------
// V transpose: qkv V slots [b*2048+t][2048 + h*64 + d] -> vT[bh][d][t]
// ---------------------------------------------------------------------------
__global__ __launch_bounds__(256) void transpose_v(const u16* __restrict__ qkv,
                                                   u16* __restrict__ vT) {
    __shared__ u16 tile[32][33];
    const int tb = blockIdx.x * 32;  // t
    const int db = blockIdx.y * 32;  // d
    const int bh = blockIdx.z;
    const int b = bh >> 4, h = bh & 15;
    const int tx = threadIdx.x, ty = threadIdx.y;  // 32 x 8
#pragma unroll
    for (int i = 0; i < 32; i += 8)
        tile[ty + i][tx] = qkv[((long)b * 2048 + tb + ty + i) * 3072 + 2048 + h * 64 + db + tx];
    __syncthreads();
#pragma unroll
    for (int i = 0; i < 32; i += 8)
        vT[((long)bh * 64 + db + ty + i) * 2048 + tb + tx] = tile[tx][ty + i];
}

// ---------------------------------------------------------------------------
// GEMM1: C[M,N](bf16) = A[M,K](bf16, lda) @ BT[N,K](bf16)^T + bias(f32)
// ---------------------------------------------------------------------------
__global__ __launch_bounds__(256, 2) void gemm_bf16_bt(
    const u16* __restrict__ A, int lda, const u16* __restrict__ BT,
    const float* __restrict__ bias, u16* __restrict__ C,
    int M, int N, int K) {
    __shared__ u16 As[128 * 32];
    __shared__ u16 Bs[128 * 32];
    const int tid = threadIdx.x;
    const int wv = tid >> 6, lane = tid & 63, quad = lane >> 4, L = lane & 15;
    const int wm = (wv >> 1) * 64, wn = (wv & 1) * 64;
    const long m0 = (long)blockIdx.y * 128;
    const long n0 = (long)blockIdx.x * 128;

    const u16* Ag = A + (m0 + wv * 32 + (lane >> 2)) * (long)lda + (lane & 3) * 8;
    const u16* Bg = BT + (n0 + wv * 32 + (lane >> 2)) * (long)K + (lane & 3) * 8;
    u16* AsW = &As[wv * 32 * 32];
    u16* BsW = &Bs[wv * 32 * 32];

    f32x4 zero4 = {0.f, 0.f, 0.f, 0.f};
    f32x4 acc[4][4];
#pragma unroll
    for (int i = 0; i < 4; ++i)
#pragma unroll
        for (int j = 0; j < 4; ++j) acc[i][j] = zero4;

    for (int kb = 0; kb < K; kb += 32) {
        short8 a0 = *(const short8*)(Ag + kb);
        short8 a1 = *(const short8*)(Ag + kb + (long)16 * lda);
        short8 b0 = *(const short8*)(Bg + kb);
        short8 b1 = *(const short8*)(Bg + kb + (long)16 * K);
        __syncthreads();
        *(short8*)(AsW + lane * 8) = a0;
        *(short8*)(AsW + 512 + lane * 8) = a1;
        *(short8*)(BsW + lane * 8) = b0;
        *(short8*)(BsW + 512 + lane * 8) = b1;
        __syncthreads();

        short8 af[4], bf[4];
#pragma unroll
        for (int mt = 0; mt < 4; ++mt)
            af[mt] = *(const short8*)&As[(wm + mt * 16 + L) * 32 + quad * 8];
#pragma unroll
        for (int nt = 0; nt < 4; ++nt)
            bf[nt] = *(const short8*)&Bs[(wn + nt * 16 + L) * 32 + quad * 8];
#pragma unroll
        for (int mt = 0; mt < 4; ++mt)
#pragma unroll
            for (int nt = 0; nt < 4; ++nt)
                acc[mt][nt] = __builtin_amdgcn_mfma_f32_16x16x32_bf16(
                    af[mt], bf[nt], acc[mt][nt], 0, 0, 0);
    }

#pragma unroll
    for (int nt = 0; nt < 4; ++nt) {
        const long col = n0 + wn + nt * 16 + L;
        const float bv = bias[col];
#pragma unroll
        for (int mt = 0; mt < 4; ++mt)
#pragma unroll
            for (int r = 0; r < 4; ++r) {
                const long row = m0 + wm + mt * 16 + quad * 4 + r;
                C[row * N + col] = f2bf(acc[mt][nt][r] + bv);
            }
    }
}

// ---------------------------------------------------------------------------
// GEMM2: C[M,N](f32) = A[M,K](bf16, lda) @ B[K,N](f32) + bias(f32)
// ---------------------------------------------------------------------------
__global__ __launch_bounds__(256, 2) void gemm_bf16_bn(
    const u16* __restrict__ A, int lda, const float* __restrict__ B,
    const float* __restrict__ bias, float* __restrict__ C,
    int M, int N, int K) {
    __shared__ u16 As[128 * 32];
    __shared__ u16 Bs[128 * 32];
    const int tid = threadIdx.x;
    const int wv = tid >> 6, lane = tid & 63, quad = lane >> 4, L = lane & 15;
    const int wm = (wv >> 1) * 64, wn = (wv & 1) * 64;
    const long m0 = (long)blockIdx.y * 128;
    const long n0 = (long)blockIdx.x * 128;

    const u16* Ag = A + (m0 + wv * 32 + (lane >> 2)) * (long)lda + (lane & 3) * 8;
    u16* AsW = &As[wv * 32 * 32];

    f32x4 zero4 = {0.f, 0.f, 0.f, 0.f};
    f32x4 acc[4][4];
#pragma unroll
    for (int i = 0; i < 4; ++i)
#pragma unroll
        for (int j = 0; j < 4; ++j) acc[i][j] = zero4;

    for (int kb = 0; kb < K; kb += 32) {
        short8 a0 = *(const short8*)(Ag + kb);
        short8 a1 = *(const short8*)(Ag + kb + (long)16 * lda);
        short8 p[2];
#pragma unroll
        for (int i = 0; i < 2; ++i) {
            const int c = tid + i * 256;
            const int n = c >> 2, k8 = (c & 3) * 8;
            const float* bp = B + (long)(kb + k8) * N + n0 + n;
#pragma unroll
            for (int j = 0; j < 8; ++j) p[i][j] = (short)f2bf(bp[(long)j * N]);
        }
        __syncthreads();
        *(short8*)(AsW + lane * 8) = a0;
        *(short8*)(AsW + 512 + lane * 8) = a1;
        *(short8*)(&Bs[tid * 8]) = p[0];
        *(short8*)(&Bs[(tid + 256) * 8]) = p[1];
        __syncthreads();

        short8 af[4], bf[4];
#pragma unroll
        for (int mt = 0; mt < 4; ++mt)
            af[mt] = *(const short8*)&As[(wm + mt * 16 + L) * 32 + quad * 8];
#pragma unroll
        for (int nt = 0; nt < 4; ++nt)
            bf[nt] = *(const short8*)&Bs[(wn + nt * 16 + L) * 32 + quad * 8];
#pragma unroll
        for (int mt = 0; mt < 4; ++mt)
#pragma unroll
            for (int nt = 0; nt < 4; ++nt)
                acc[mt][nt] = __builtin_amdgcn_mfma_f32_16x16x32_bf16(
                    af[mt], bf[nt], acc[mt][nt], 0, 0, 0);
    }

#pragma unroll
    for (int nt = 0; nt < 4; ++nt) {
        const long col = n0 + wn + nt * 16 + L;
        const float bv = bias[col];
#pragma unroll
        for (int mt = 0; mt < 4; ++mt)
#pragma unroll
            for (int r = 0; r < 4; ++r) {
                const long row = m0 + wm + mt * 16 + quad * 4 + r;
                C[row * N + col] = acc[mt][nt][r] + bv;
            }
    }
}

// ---------------------------------------------------------------------------
// Flash attention (causal), bf16, fixed-max softmax (m=20), IN-REGISTER
// softmax path (m214/T12 structure):
//   - 4 waves x 32 queries (qtile = 128), 32-key tiles, grid 64 x 8 paired
//     (15-by, by) -> constant 68 staged tiles/block.
//   - swapped QK^T on 32x32x16 MFMA: S[key][q], col = lane&31 = q, so each
//     lane's 16 acc regs are P values of ONE query column -> lane-local.
//   - P -> bf16 A-fragment built in registers: 8 cvt_pk_bf16 + 4
//     permlane32_swap per tile. NO P LDS round trip (Ps buffer deleted;
//     that round trip was ~all of the 1.17e7 bank conflicts).
//   - row-sum l via ones-column MFMA (2 per tile); PV: 4 MFMA; QK: 4 MFMA.
//   - K/V staged double-buffered in LDS (pitches 72/40, conflict-free at the
//     b128 8-phase floor), register prefetch one tile ahead, ONE barrier/tile.
// Output written into the Q slots of qkv (race-free: disjoint q-ownership).
// ---------------------------------------------------------------------------
#define AT_T 2048

__global__ __launch_bounds__(256) void attn_kernel(u16* __restrict__ qkv,
                                                   const u16* __restrict__ vT) {
    __shared__ u16 Kt[2][32 * 72];   // [key][d]  tile, pitch 72
    __shared__ u16 Vt[2][64 * 40];   // [d][key]  tile, pitch 40
    const int tid = threadIdx.x;
    const int wv = tid >> 6, lane = tid & 63;
    const int hi = lane >> 5, cc = lane & 31;
    const int bh = blockIdx.x;
    const int b = bh >> 4, h = bh & 15;
    const long rowbase = (long)b * AT_T;
    const long cbase = (long)h * 64;

    // staging geometry (coalesced: consecutive tid -> consecutive 16B)
    const int krow = tid >> 3, kc = tid & 7;  // K: 32 rows x 8 chunks
    const int vrow = tid >> 2, vc = tid & 3;  // V: 64 rows x 4 chunks
    const u16* Kg = qkv + (rowbase + krow) * 3072 + 1024 + cbase + kc * 8;
    const u16* Vg = vT + ((long)bh * 64 + vrow) * 2048 + vc * 8;

    // ones B-fragment: column 0 accumulates row sums
    short8 ones;
#pragma unroll
    for (int j = 0; j < 8; ++j) ones[j] = (cc == 0) ? (short)0x3F80 : (short)0;

    const float C1 = 0.18033688f;    //  0.125 * log2(e)
    const float C0 = -28.8539008f;   // -20    * log2(e)

    for (int pass = 0; pass < 2; ++pass) {
        const int qt = (pass == 0) ? (15 - (int)blockIdx.y) : (int)blockIdx.y;
        const int q0 = qt * 128;
        const int qw = q0 + wv * 32;  // this wave's 32 queries
        const int nkb = 4 * qt + 4;

        // Q as B-fragment: lane holds Q[q = cc][d = ks*16 + hi*8 + j]
        short8 qf[4];
#pragma unroll
        for (int ks = 0; ks < 4; ++ks)
            qf[ks] = *(const short8*)&qkv[(rowbase + qw + cc) * 3072 + cbase + ks * 16 + hi * 8];

        f32x16 accO0, accO1, accL;
#pragma unroll
        for (int r = 0; r < 16; ++r) { accO0[r] = 0.f; accO1[r] = 0.f; accL[r] = 0.f; }

        // preload tile 0 into buf 0
        {
            short8 k0r = *(const short8*)Kg;
            short8 v0r = *(const short8*)Vg;
            *(short8*)&Kt[0][krow * 72 + kc * 8] = k0r;
            *(short8*)&Vt[0][vrow * 40 + vc * 8] = v0r;
        }
        __syncthreads();

        int p = 0;
        for (int kb = 0; kb < nkb; ++kb) {
            const int k0 = kb * 32;
            const bool more = (kb + 1) < nkb;
            short8 knx, vnx;
            if (more) {
                knx = *(const short8*)(Kg + (long)(k0 + 32) * 3072);
                vnx = *(const short8*)(Vg + k0 + 32);
            }

            if (k0 <= qw) {  // tile has unmasked work for this wave
                // swapped QK^T: S[key][q], A = K-tile, B = Q-frag
                f32x16 s;
#pragma unroll
                for (int r = 0; r < 16; ++r) s[r] = 0.f;
#pragma unroll
                for (int ks = 0; ks < 4; ++ks) {
                    short8 kf = *(const short8*)&Kt[p][cc * 72 + ks * 16 + hi * 8];
                    s = __builtin_amdgcn_mfma_f32_32x32x16_bf16(kf, qf[ks], s, 0, 0, 0);
                }
                // p = exp2(s*0.125*log2e - 20*log2e); reg r holds
                // P[key = (r&3)+8*(r>>2)+4*hi][q = cc]
                float pe[16];
                if (k0 == qw) {  // diagonal tile: mask key > q
#pragma unroll
                    for (int r = 0; r < 16; ++r) {
                        const int key = (r & 3) + 8 * (r >> 2) + 4 * hi;
                        const float e = EXP2F(fmaf(s[r], C1, C0));
                        pe[r] = (key <= cc) ? e : 0.f;
                    }
                } else {
#pragma unroll
                    for (int r = 0; r < 16; ++r) pe[r] = EXP2F(fmaf(s[r], C1, C0));
                }

                // in-register P -> PV A-fragment (per 16-key slot ks):
                // dword d of a-frag = pack(regs 8ks+4hi+{2d&2,+1}) from lane
                // half (d>>1); one permlane32_swap fills dwords (d, d+2).
                short8 pa[2];
#pragma unroll
                for (int ks = 0; ks < 2; ++ks) {
                    u32 wA = cvt_pk_bf16(pe[8 * ks + 0], pe[8 * ks + 1]);
                    u32 wB = cvt_pk_bf16(pe[8 * ks + 2], pe[8 * ks + 3]);
                    u32 wC = cvt_pk_bf16(pe[8 * ks + 4], pe[8 * ks + 5]);
                    u32 wD = cvt_pk_bf16(pe[8 * ks + 6], pe[8 * ks + 7]);
                    pswap(wA, wC);  // -> dword0, dword2
                    pswap(wB, wD);  // -> dword1, dword3
                    union { u32 d[4]; short8 v; } u;
                    u.d[0] = wA; u.d[1] = wB; u.d[2] = wC; u.d[3] = wD;
                    pa[ks] = u.v;
                }

                // row sums (column 0 of accL) + PV
                accL = __builtin_amdgcn_mfma_f32_32x32x16_bf16(pa[0], ones, accL, 0, 0, 0);
                accL = __builtin_amdgcn_mfma_f32_32x32x16_bf16(pa[1], ones, accL, 0, 0, 0);
#pragma unroll
                for (int ks = 0; ks < 2; ++ks) {
                    short8 vf0 = *(const short8*)&Vt[p][cc * 40 + ks * 16 + hi * 8];
                    short8 vf1 = *(const short8*)&Vt[p][(32 + cc) * 40 + ks * 16 + hi * 8];
                    accO0 = __builtin_amdgcn_mfma_f32_32x32x16_bf16(pa[ks], vf0, accO0, 0, 0, 0);
                    accO1 = __builtin_amdgcn_mfma_f32_32x32x16_bf16(pa[ks], vf1, accO1, 0, 0, 0);
                }
            }

            // write prefetched tile into the other buffer
            if (more) {
                *(short8*)&Kt[p ^ 1][krow * 72 + kc * 8] = knx;
                *(short8*)&Vt[p ^ 1][vrow * 40 + vc * 8] = vnx;
            }
            __syncthreads();
            p ^= 1;
        }

        // normalize + write into Q slots.
        // accO{0,1}[r] = O[q = crow(r,hi)][d = {0,32} + cc];
        // l[q] lives at lane hi*32 (col 0), reg r.
#pragma unroll
        for (int r = 0; r < 16; ++r) {
            const float l = __shfl(accL[r], lane & 32);
            const float inv = 1.f / l;
            const int q = (r & 3) + 8 * (r >> 2) + 4 * hi;
            const long orow = (rowbase + qw + q) * 3072 + cbase;
            qkv[orow + cc] = f2bf(accO0[r] * inv);
            qkv[orow + 32 + cc] = f2bf(accO1[r] * inv);
        }
    }
}

// ---------------------------------------------------------------------------
extern "C" void kernel_launch(void* const* d_in, const int* in_sizes, int n_in,
                              void* d_out, int out_size, void* d_ws, size_t ws_size,
                              hipStream_t stream) {
    const float* x      = (const float*)d_in[0];
    const float* w_attn = (const float*)d_in[1];
    const float* b_attn = (const float*)d_in[2];
    const float* w_proj = (const float*)d_in[3];
    const float* b_proj = (const float*)d_in[4];
    float* out = (float*)d_out;

    u16* qkv = (u16*)d_ws;                      // [8192,3072] bf16 (50.33 MB)
    u16* xb  = (u16*)d_out;                     // [8192,1024] bf16 scratch (dies at GEMM1)
    u16* wTa = (u16*)((char*)d_out + 16777216); // [3072,1024] bf16 scratch (dies at GEMM1)
    u16* vT  = (u16*)d_out;                     // [64,64,2048] bf16 scratch (dies at GEMM2)

    convert_bf16<<<4096, 256, 0, stream>>>(x, xb);
    transpose_f32_bf16<<<dim3(3072 / 32, 1024 / 32), dim3(32, 8), 0, stream>>>(
        w_attn, wTa, 1024, 3072);
    gemm_bf16_bt<<<dim3(3072 / 128, 8192 / 128), 256, 0, stream>>>(
        xb, 1024, wTa, b_attn, qkv, 8192, 3072, 1024);
    transpose_v<<<dim3(64, 2, 64), dim3(32, 8), 0, stream>>>(qkv, vT);
    attn_kernel<<<dim3(64, 8), 256, 0, stream>>>(qkv, vT);
    gemm_bf16_bn<<<dim3(1024 / 128, 8192 / 128), 256, 0, stream>>>(
        qkv, 3072, w_proj, b_proj, out, 8192, 1024, 1024);
}

// Round 4
// 273.117 us; speedup vs baseline: 1.0920x; 1.0920x over previous
//
#include <hip/hip_runtime.h>

typedef __attribute__((ext_vector_type(8))) short short8;
typedef __attribute__((ext_vector_type(4))) float f32x4;
typedef __attribute__((ext_vector_type(16))) float f32x16;
typedef unsigned short u16;
typedef unsigned int u32;

__device__ __forceinline__ float bf2f(u16 u) {
    union { u32 i; float f; } x;
    x.i = ((u32)u) << 16;
    return x.f;
}

__device__ __forceinline__ u16 f2bf(float f) {
    union { float f; u32 i; } x;
    x.f = f;
    u32 r = x.i + 0x7fffu + ((x.i >> 16) & 1u);  // RNE
    return (u16)(r >> 16);
}

// packed f32x2 -> bf16x2 (RNE), one instruction
__device__ __forceinline__ u32 cvt_pk_bf16(float lo, float hi) {
    u32 d;
    asm("v_cvt_pk_bf16_f32 %0, %1, %2" : "=v"(d) : "v"(lo), "v"(hi));
    return d;
}

// after pswap(a,b):  a' = lane<32 ? a(own) : b(lane-32)
//                    b' = lane<32 ? a(lane+32) : b(own)
__device__ __forceinline__ void pswap(u32& a, u32& b) {
#if __has_builtin(__builtin_amdgcn_permlane32_swap)
    auto r = __builtin_amdgcn_permlane32_swap(a, b, false, false);
    a = r[0];
    b = r[1];
#else
    const int l = (int)(threadIdx.x & 63);
    const u32 ax = __shfl(a, l ^ 32);
    const u32 bx = __shfl(b, l ^ 32);
    a = (l < 32) ? a : bx;
    b = (l < 32) ? ax : b;
#endif
}

#if __has_builtin(__builtin_amdgcn_exp2f)
#define EXP2F(x) __builtin_amdgcn_exp2f(x)
#else
#define EXP2F(x) exp2f(x)
#endif

// softmax scale folded into K at GEMM1 epilogue: 0.125 * log2(e)
#define K_SCALE 0.18033688f

// ---------------------------------------------------------------------------
// fp32 -> bf16 elementwise (n divisible by 2048)
// ---------------------------------------------------------------------------
__global__ __launch_bounds__(256) void convert_bf16(const float* __restrict__ in,
                                                    u16* __restrict__ out) {
    const long i = ((long)blockIdx.x * 256 + threadIdx.x) * 8;
    f32x4 v0 = *(const f32x4*)(in + i);
    f32x4 v1 = *(const f32x4*)(in + i + 4);
    short8 o;
#pragma unroll
    for (int j = 0; j < 4; ++j) o[j] = (short)f2bf(v0[j]);
#pragma unroll
    for (int j = 0; j < 4; ++j) o[4 + j] = (short)f2bf(v1[j]);
    *(short8*)(out + i) = o;
}

// ---------------------------------------------------------------------------
// fp32 [K][N] -> bf16 [N][K] transpose+convert
// ---------------------------------------------------------------------------
__global__ __launch_bounds__(256) void transpose_f32_bf16(const float* __restrict__ in,
                                                          u16* __restrict__ out,
                                                          int K, int N) {
    __shared__ float tile[32][33];
    const int nb = blockIdx.x * 32, kb = blockIdx.y * 32;
    const int tx = threadIdx.x, ty = threadIdx.y;  // 32 x 8
#pragma unroll
    for (int i = 0; i < 32; i += 8)
        tile[ty + i][tx] = in[(long)(kb + ty + i) * N + nb + tx];
    __syncthreads();
#pragma unroll
    for (int i = 0; i < 32; i += 8)
        out[(long)(nb + ty + i) * K + kb + tx] = f2bf(tile[tx][ty + i]);
}

// ---------------------------------------------------------------------------
// V transpose: qkv V slots [b*2048+t][2048 + h*64 + d] -> vT[bh][d][t]
// ---------------------------------------------------------------------------
__global__ __launch_bounds__(256) void transpose_v(const u16* __restrict__ qkv,
                                                   u16* __restrict__ vT) {
    __shared__ u16 tile[32][33];
    const int tb = blockIdx.x * 32;  // t
    const int db = blockIdx.y * 32;  // d
    const int bh = blockIdx.z;
    const int b = bh >> 4, h = bh & 15;
    const int tx = threadIdx.x, ty = threadIdx.y;  // 32 x 8
#pragma unroll
    for (int i = 0; i < 32; i += 8)
        tile[ty + i][tx] = qkv[((long)b * 2048 + tb + ty + i) * 3072 + 2048 + h * 64 + db + tx];
    __syncthreads();
#pragma unroll
    for (int i = 0; i < 32; i += 8)
        vT[((long)bh * 64 + db + ty + i) * 2048 + tb + tx] = tile[tx][ty + i];
}

// ---------------------------------------------------------------------------
// GEMM1: C[M,N](bf16) = A[M,K](bf16, lda) @ BT[N,K](bf16)^T + bias(f32)
// K-slot columns [1024,2048) are pre-scaled by K_SCALE (softmax scale fold).
// ---------------------------------------------------------------------------
__global__ __launch_bounds__(256, 2) void gemm_bf16_bt(
    const u16* __restrict__ A, int lda, const u16* __restrict__ BT,
    const float* __restrict__ bias, u16* __restrict__ C,
    int M, int N, int K) {
    __shared__ u16 As[128 * 32];
    __shared__ u16 Bs[128 * 32];
    const int tid = threadIdx.x;
    const int wv = tid >> 6, lane = tid & 63, quad = lane >> 4, L = lane & 15;
    const int wm = (wv >> 1) * 64, wn = (wv & 1) * 64;
    const long m0 = (long)blockIdx.y * 128;
    const long n0 = (long)blockIdx.x * 128;

    const u16* Ag = A + (m0 + wv * 32 + (lane >> 2)) * (long)lda + (lane & 3) * 8;
    const u16* Bg = BT + (n0 + wv * 32 + (lane >> 2)) * (long)K + (lane & 3) * 8;
    u16* AsW = &As[wv * 32 * 32];
    u16* BsW = &Bs[wv * 32 * 32];

    f32x4 zero4 = {0.f, 0.f, 0.f, 0.f};
    f32x4 acc[4][4];
#pragma unroll
    for (int i = 0; i < 4; ++i)
#pragma unroll
        for (int j = 0; j < 4; ++j) acc[i][j] = zero4;

    for (int kb = 0; kb < K; kb += 32) {
        short8 a0 = *(const short8*)(Ag + kb);
        short8 a1 = *(const short8*)(Ag + kb + (long)16 * lda);
        short8 b0 = *(const short8*)(Bg + kb);
        short8 b1 = *(const short8*)(Bg + kb + (long)16 * K);
        __syncthreads();
        *(short8*)(AsW + lane * 8) = a0;
        *(short8*)(AsW + 512 + lane * 8) = a1;
        *(short8*)(BsW + lane * 8) = b0;
        *(short8*)(BsW + 512 + lane * 8) = b1;
        __syncthreads();

        short8 af[4], bf[4];
#pragma unroll
        for (int mt = 0; mt < 4; ++mt)
            af[mt] = *(const short8*)&As[(wm + mt * 16 + L) * 32 + quad * 8];
#pragma unroll
        for (int nt = 0; nt < 4; ++nt)
            bf[nt] = *(const short8*)&Bs[(wn + nt * 16 + L) * 32 + quad * 8];
#pragma unroll
        for (int mt = 0; mt < 4; ++mt)
#pragma unroll
            for (int nt = 0; nt < 4; ++nt)
                acc[mt][nt] = __builtin_amdgcn_mfma_f32_16x16x32_bf16(
                    af[mt], bf[nt], acc[mt][nt], 0, 0, 0);
    }

#pragma unroll
    for (int nt = 0; nt < 4; ++nt) {
        const long col = n0 + wn + nt * 16 + L;
        const float bv = bias[col];
        const float scl = (col >= 1024 && col < 2048) ? K_SCALE : 1.0f;
#pragma unroll
        for (int mt = 0; mt < 4; ++mt)
#pragma unroll
            for (int r = 0; r < 4; ++r) {
                const long row = m0 + wm + mt * 16 + quad * 4 + r;
                C[row * N + col] = f2bf((acc[mt][nt][r] + bv) * scl);
            }
    }
}

// ---------------------------------------------------------------------------
// GEMM2: C[M,N](f32) = A[M,K](bf16, lda) @ B[K,N](f32) + bias(f32)
// ---------------------------------------------------------------------------
__global__ __launch_bounds__(256, 2) void gemm_bf16_bn(
    const u16* __restrict__ A, int lda, const float* __restrict__ B,
    const float* __restrict__ bias, float* __restrict__ C,
    int M, int N, int K) {
    __shared__ u16 As[128 * 32];
    __shared__ u16 Bs[128 * 32];
    const int tid = threadIdx.x;
    const int wv = tid >> 6, lane = tid & 63, quad = lane >> 4, L = lane & 15;
    const int wm = (wv >> 1) * 64, wn = (wv & 1) * 64;
    const long m0 = (long)blockIdx.y * 128;
    const long n0 = (long)blockIdx.x * 128;

    const u16* Ag = A + (m0 + wv * 32 + (lane >> 2)) * (long)lda + (lane & 3) * 8;
    u16* AsW = &As[wv * 32 * 32];

    f32x4 zero4 = {0.f, 0.f, 0.f, 0.f};
    f32x4 acc[4][4];
#pragma unroll
    for (int i = 0; i < 4; ++i)
#pragma unroll
        for (int j = 0; j < 4; ++j) acc[i][j] = zero4;

    for (int kb = 0; kb < K; kb += 32) {
        short8 a0 = *(const short8*)(Ag + kb);
        short8 a1 = *(const short8*)(Ag + kb + (long)16 * lda);
        short8 p[2];
#pragma unroll
        for (int i = 0; i < 2; ++i) {
            const int c = tid + i * 256;
            const int n = c >> 2, k8 = (c & 3) * 8;
            const float* bp = B + (long)(kb + k8) * N + n0 + n;
            float f[8];
#pragma unroll
            for (int j = 0; j < 8; ++j) f[j] = bp[(long)j * N];
            union { u32 d[4]; short8 v; } u;
#pragma unroll
            for (int j = 0; j < 4; ++j) u.d[j] = cvt_pk_bf16(f[2 * j], f[2 * j + 1]);
            p[i] = u.v;
        }
        __syncthreads();
        *(short8*)(AsW + lane * 8) = a0;
        *(short8*)(AsW + 512 + lane * 8) = a1;
        *(short8*)(&Bs[tid * 8]) = p[0];
        *(short8*)(&Bs[(tid + 256) * 8]) = p[1];
        __syncthreads();

        short8 af[4], bf[4];
#pragma unroll
        for (int mt = 0; mt < 4; ++mt)
            af[mt] = *(const short8*)&As[(wm + mt * 16 + L) * 32 + quad * 8];
#pragma unroll
        for (int nt = 0; nt < 4; ++nt)
            bf[nt] = *(const short8*)&Bs[(wn + nt * 16 + L) * 32 + quad * 8];
#pragma unroll
        for (int mt = 0; mt < 4; ++mt)
#pragma unroll
            for (int nt = 0; nt < 4; ++nt)
                acc[mt][nt] = __builtin_amdgcn_mfma_f32_16x16x32_bf16(
                    af[mt], bf[nt], acc[mt][nt], 0, 0, 0);
    }

#pragma unroll
    for (int nt = 0; nt < 4; ++nt) {
        const long col = n0 + wn + nt * 16 + L;
        const float bv = bias[col];
#pragma unroll
        for (int mt = 0; mt < 4; ++mt)
#pragma unroll
            for (int r = 0; r < 4; ++r) {
                const long row = m0 + wm + mt * 16 + quad * 4 + r;
                C[row * N + col] = acc[mt][nt][r] + bv;
            }
    }
}

// ---------------------------------------------------------------------------
// Flash attention (causal), bf16, in-register softmax (m214/T12 structure).
//   - 4 waves x 32 queries (qtile = 128), grid 64 x 8 paired (15-by, by).
//   - 64-key STAGED tiles (two 32-key compute halves per stage): half the
//     barriers/loop iterations vs 32-key staging, 2x latency cover for the
//     one-stage-ahead register prefetch. LDS 36 KB double-buffered.
//   - swapped QK^T on 32x32x16 MFMA: S[key][q]; P lane-local per q-column.
//   - P -> PV A-frag in registers: 8 cvt_pk + 4 permlane32_swap per half.
//   - softmax scale pre-folded into K (GEMM1 epilogue); no fixed-max bias
//     (constant bias cancels in O/l): pe = exp2(s), no fmaf.
//   - zero accumulator hoisted (z16) -> no per-tile s zero-init movs.
// NOTE (R3 bug fix): V prefetch second half advances the d dimension
// (+32*2048), matching the preload — NOT the key offset.
// Output written into the Q slots of qkv (race-free: disjoint q-ownership).
// ---------------------------------------------------------------------------
#define AT_T 2048

__global__ __launch_bounds__(256) void attn_kernel(u16* __restrict__ qkv,
                                                   const u16* __restrict__ vT) {
    __shared__ u16 Kt[2][64 * 72];   // [key][d]  tile, pitch 72
    __shared__ u16 Vt[2][64 * 72];   // [d][key]  tile, pitch 72
    const int tid = threadIdx.x;
    const int wv = tid >> 6, lane = tid & 63;
    const int hi = lane >> 5, cc = lane & 31;
    const int bh = blockIdx.x;
    const int b = bh >> 4, h = bh & 15;
    const long rowbase = (long)b * AT_T;
    const long cbase = (long)h * 64;

    // staging geometry: thread covers rows (r, r+32), 8 chunks of 8 per row
    const int srow = tid >> 3, sc = tid & 7;  // 32 rows x 8 chunks, x2 rows
    const u16* Kg = qkv + (rowbase + srow) * 3072 + 1024 + cbase + sc * 8;
    const u16* Vg = vT + ((long)bh * 64 + srow) * 2048 + sc * 8;
    const int kLo = srow * 72 + sc * 8, kHi = (srow + 32) * 72 + sc * 8;

    // ones B-fragment: column 0 accumulates row sums
    short8 ones;
#pragma unroll
    for (int j = 0; j < 8; ++j) ones[j] = (cc == 0) ? (short)0x3F80 : (short)0;

    f32x16 z16;
#pragma unroll
    for (int r = 0; r < 16; ++r) z16[r] = 0.f;

    for (int pass = 0; pass < 2; ++pass) {
        const int qt = (pass == 0) ? (15 - (int)blockIdx.y) : (int)blockIdx.y;
        const int qw = qt * 128 + wv * 32;  // this wave's 32 queries
        const int nkb = 2 * qt + 2;         // staged 64-key tiles

        // Q as B-fragment: lane holds Q[q = cc][d = ks*16 + hi*8 + j]
        short8 qf[4];
#pragma unroll
        for (int ks = 0; ks < 4; ++ks)
            qf[ks] = *(const short8*)&qkv[(rowbase + qw + cc) * 3072 + cbase + ks * 16 + hi * 8];

        f32x16 accO0, accO1, accL;
#pragma unroll
        for (int r = 0; r < 16; ++r) { accO0[r] = 0.f; accO1[r] = 0.f; accL[r] = 0.f; }

        // preload tile 0 into buf 0
        {
            *(short8*)&Kt[0][kLo] = *(const short8*)Kg;
            *(short8*)&Kt[0][kHi] = *(const short8*)(Kg + (long)32 * 3072);
            *(short8*)&Vt[0][kLo] = *(const short8*)Vg;
            *(short8*)&Vt[0][kHi] = *(const short8*)(Vg + (long)32 * 2048);
        }
        __syncthreads();

        int p = 0;
        for (int kb = 0; kb < nkb; ++kb) {
            const int k0 = kb * 64;
            const bool more = (kb + 1) < nkb;
            short8 kn0, kn1, vn0, vn1;
            if (more) {
                kn0 = *(const short8*)(Kg + (long)(k0 + 64) * 3072);
                kn1 = *(const short8*)(Kg + (long)(k0 + 96) * 3072);
                vn0 = *(const short8*)(Vg + k0 + 64);
                vn1 = *(const short8*)(Vg + (long)32 * 2048 + k0 + 64);
            }

#pragma unroll
            for (int hh = 0; hh < 2; ++hh) {
                const int kh = k0 + 32 * hh;
                if (kh <= qw) {  // half has unmasked work for this wave
                    // swapped QK^T: S[key][q], A = K rows (32hh + cc)
                    f32x16 s;
                    {
                        short8 kf = *(const short8*)&Kt[p][(32 * hh + cc) * 72 + hi * 8];
                        s = __builtin_amdgcn_mfma_f32_32x32x16_bf16(kf, qf[0], z16, 0, 0, 0);
                    }
#pragma unroll
                    for (int ks = 1; ks < 4; ++ks) {
                        short8 kf = *(const short8*)&Kt[p][(32 * hh + cc) * 72 + ks * 16 + hi * 8];
                        s = __builtin_amdgcn_mfma_f32_32x32x16_bf16(kf, qf[ks], s, 0, 0, 0);
                    }
                    // pe = exp2(s)  (K pre-scaled by 0.125*log2e; no bias)
                    float pe[16];
                    if (kh == qw) {  // diagonal half: mask key > q
#pragma unroll
                        for (int r = 0; r < 16; ++r) {
                            const int key = (r & 3) + 8 * (r >> 2) + 4 * hi;
                            const float e = EXP2F(s[r]);
                            pe[r] = (key <= cc) ? e : 0.f;
                        }
                    } else {
#pragma unroll
                        for (int r = 0; r < 16; ++r) pe[r] = EXP2F(s[r]);
                    }

                    // in-register P -> PV A-fragment (two 16-key slots)
                    short8 pa[2];
#pragma unroll
                    for (int ks = 0; ks < 2; ++ks) {
                        u32 wA = cvt_pk_bf16(pe[8 * ks + 0], pe[8 * ks + 1]);
                        u32 wB = cvt_pk_bf16(pe[8 * ks + 2], pe[8 * ks + 3]);
                        u32 wC = cvt_pk_bf16(pe[8 * ks + 4], pe[8 * ks + 5]);
                        u32 wD = cvt_pk_bf16(pe[8 * ks + 6], pe[8 * ks + 7]);
                        pswap(wA, wC);  // -> dword0, dword2
                        pswap(wB, wD);  // -> dword1, dword3
                        union { u32 d[4]; short8 v; } u;
                        u.d[0] = wA; u.d[1] = wB; u.d[2] = wC; u.d[3] = wD;
                        pa[ks] = u.v;
                    }

                    // row sums (column 0 of accL) + PV
                    accL = __builtin_amdgcn_mfma_f32_32x32x16_bf16(pa[0], ones, accL, 0, 0, 0);
                    accL = __builtin_amdgcn_mfma_f32_32x32x16_bf16(pa[1], ones, accL, 0, 0, 0);
#pragma unroll
                    for (int ks = 0; ks < 2; ++ks) {
                        short8 vf0 = *(const short8*)&Vt[p][cc * 72 + 32 * hh + ks * 16 + hi * 8];
                        short8 vf1 = *(const short8*)&Vt[p][(32 + cc) * 72 + 32 * hh + ks * 16 + hi * 8];
                        accO0 = __builtin_amdgcn_mfma_f32_32x32x16_bf16(pa[ks], vf0, accO0, 0, 0, 0);
                        accO1 = __builtin_amdgcn_mfma_f32_32x32x16_bf16(pa[ks], vf1, accO1, 0, 0, 0);
                    }
                }
            }

            // write prefetched tile into the other buffer
            if (more) {
                *(short8*)&Kt[p ^ 1][kLo] = kn0;
                *(short8*)&Kt[p ^ 1][kHi] = kn1;
                *(short8*)&Vt[p ^ 1][kLo] = vn0;
                *(short8*)&Vt[p ^ 1][kHi] = vn1;
            }
            __syncthreads();
            p ^= 1;
        }

        // normalize + write into Q slots.
        // accO{0,1}[r] = O[q = crow(r,hi)][d = {0,32} + cc];
        // l[q] lives at lane hi*32 (col 0), reg r.
#pragma unroll
        for (int r = 0; r < 16; ++r) {
            const float l = __shfl(accL[r], lane & 32);
            const float inv = 1.f / l;
            const int q = (r & 3) + 8 * (r >> 2) + 4 * hi;
            const long orow = (rowbase + qw + q) * 3072 + cbase;
            qkv[orow + cc] = f2bf(accO0[r] * inv);
            qkv[orow + 32 + cc] = f2bf(accO1[r] * inv);
        }
    }
}

// ---------------------------------------------------------------------------
extern "C" void kernel_launch(void* const* d_in, const int* in_sizes, int n_in,
                              void* d_out, int out_size, void* d_ws, size_t ws_size,
                              hipStream_t stream) {
    const float* x      = (const float*)d_in[0];
    const float* w_attn = (const float*)d_in[1];
    const float* b_attn = (const float*)d_in[2];
    const float* w_proj = (const float*)d_in[3];
    const float* b_proj = (const float*)d_in[4];
    float* out = (float*)d_out;

    u16* qkv = (u16*)d_ws;                      // [8192,3072] bf16 (50.33 MB)
    u16* xb  = (u16*)d_out;                     // [8192,1024] bf16 scratch (dies at GEMM1)
    u16* wTa = (u16*)((char*)d_out + 16777216); // [3072,1024] bf16 scratch (dies at GEMM1)
    u16* vT  = (u16*)d_out;                     // [64,64,2048] bf16 scratch (dies at GEMM2)

    convert_bf16<<<4096, 256, 0, stream>>>(x, xb);
    transpose_f32_bf16<<<dim3(3072 / 32, 1024 / 32), dim3(32, 8), 0, stream>>>(
        w_attn, wTa, 1024, 3072);
    gemm_bf16_bt<<<dim3(3072 / 128, 8192 / 128), 256, 0, stream>>>(
        xb, 1024, wTa, b_attn, qkv, 8192, 3072, 1024);
    transpose_v<<<dim3(64, 2, 64), dim3(32, 8), 0, stream>>>(qkv, vT);
    attn_kernel<<<dim3(64, 8), 256, 0, stream>>>(qkv, vT);
    gemm_bf16_bn<<<dim3(1024 / 128, 8192 / 128), 256, 0, stream>>>(
        qkv, 3072, w_proj, b_proj, out, 8192, 1024, 1024);
}